// Round 1
// 684.888 us; speedup vs baseline: 1.2551x; 1.2551x over previous
//
#include <hip/hip_runtime.h>
#include <stdint.h>

#define H_DIM 256
#define NCOL 8192
#define TOPK 512
#define CAND_CAP 8192

typedef unsigned short u16;
typedef __attribute__((ext_vector_type(8))) __bf16 bf16x8;
typedef __attribute__((ext_vector_type(4))) float f32x4;
typedef unsigned __attribute__((address_space(3))) lds_u32;
typedef const unsigned __attribute__((address_space(1))) glb_u32;

// monotonic float -> uint key (order-preserving for all finite floats)
__device__ __forceinline__ unsigned fkey(float f) {
  unsigned u = __float_as_uint(f);
  unsigned m = (unsigned)((int)u >> 31) | 0x80000000u;
  return u ^ m;
}

__device__ __forceinline__ u16 f2bf_rne(float f) {
  unsigned u = __float_as_uint(f);
  return (u16)((u + 0x7fffu + ((u >> 16) & 1u)) >> 16);
}

__device__ __forceinline__ float bf2f(u16 h) {
  return __uint_as_float(((unsigned)h) << 16);
}

__global__ __launch_bounds__(256) void zero_ws(unsigned* __restrict__ ghist,
                                               unsigned* __restrict__ counter) {
  int t = blockIdx.x * blockDim.x + threadIdx.x;
  if (t < 4096) ghist[t] = 0;
  if (t == 0) *counter = 0;
}

// ---------------- MLP layer: Y[rows,256] = act(X[rows,K] @ W[K,256] + b) ----------------
// block = 16 rows x 256 cols(threads). EMIT additionally writes bf16 hi/lo split of Y.
template <int K, bool RELU, bool EMIT>
__global__ __launch_bounds__(256) void mlp_layer(const float* __restrict__ X,
                                                 const float* __restrict__ W,
                                                 const float* __restrict__ bias,
                                                 float* __restrict__ Y,
                                                 u16* __restrict__ hi,
                                                 u16* __restrict__ lo) {
  __shared__ float Xs[16 * K];
  const int t = threadIdx.x;
  const int row0 = blockIdx.x * 16;
  for (int f = t; f < 4 * K; f += 256) {  // 16*K/4 float4s
    *(float4*)(Xs + f * 4) = *(const float4*)(X + row0 * K + f * 4);
  }
  __syncthreads();
  float acc[16];
#pragma unroll
  for (int r = 0; r < 16; r++) acc[r] = 0.f;
  for (int d = 0; d < K; d += 4) {
    float w0 = W[(d + 0) * H_DIM + t];
    float w1 = W[(d + 1) * H_DIM + t];
    float w2 = W[(d + 2) * H_DIM + t];
    float w3 = W[(d + 3) * H_DIM + t];
#pragma unroll
    for (int r = 0; r < 16; r++) {
      float4 x = *(const float4*)(Xs + r * K + d);
      acc[r] = fmaf(x.x, w0, acc[r]);
      acc[r] = fmaf(x.y, w1, acc[r]);
      acc[r] = fmaf(x.z, w2, acc[r]);
      acc[r] = fmaf(x.w, w3, acc[r]);
    }
  }
  const float bv = bias[t];
#pragma unroll
  for (int r = 0; r < 16; r++) {
    float v = acc[r] + bv;
    if (RELU) v = fmaxf(v, 0.f);
    Y[(row0 + r) * H_DIM + t] = v;
    if (EMIT) {
      u16 h = f2bf_rne(v);
      u16 l = f2bf_rne(v - bf2f(h));
      hi[(row0 + r) * H_DIM + t] = h;
      lo[(row0 + r) * H_DIM + t] = l;
    }
  }
}

// ---------------- big GEMM (bf16x3 MFMA): C = Ah*Bh^T + Ah*Bl^T + Al*Bh^T, fused histogram ----
// 128x128 tile, 256 threads (4 waves of 64x64), BK=32, mfma_f32_16x16x32_bf16,
// global_load_lds width-16 staging, m97 2-barrier structure, XCD-aware block swizzle.
__global__ __launch_bounds__(256) void gemm_sim_mfma(const u16* __restrict__ Ah,
                                                     const u16* __restrict__ Al,
                                                     const u16* __restrict__ Bh,
                                                     const u16* __restrict__ Bl,
                                                     float* __restrict__ C,
                                                     unsigned* __restrict__ ghist) {
  __shared__ __align__(16) u16 As[128 * 32];  // [row][k] 8KB
  __shared__ __align__(16) u16 Bs[128 * 32];  // [col-row][k] 8KB
  __shared__ unsigned hist[4096];             // 16KB  (total 32KB)
  const int t = threadIdx.x;
  const int wave = t >> 6, lane = t & 63;
  // XCD swizzle: 4096 blocks, 8 XCDs -> each XCD gets 8 contiguous tile-rows
  const int bid = blockIdx.x;
  const int swz = (bid & 7) * 512 + (bid >> 3);
  const int m0 = (swz >> 6) * 128, n0 = (swz & 63) * 128;
  for (int i = t; i < 4096; i += 256) hist[i] = 0;

  f32x4 acc[4][4];
#pragma unroll
  for (int i = 0; i < 4; i++)
#pragma unroll
    for (int j = 0; j < 4; j++) acc[i][j] = (f32x4){0.f, 0.f, 0.f, 0.f};

  const int wm = wave >> 1, wn = wave & 1;
  // staging: 512 chunks of 16B per tile; wave w instr j covers chunks [(2w+j)*64, +64)
  const int c0 = wave * 128 + lane, c1 = c0 + 64;
  const int rA0 = c0 >> 2, ko0 = (c0 & 3) * 8;
  const int rA1 = c1 >> 2, ko1 = (c1 & 3) * 8;
  u16* ldsA0 = As + wave * 1024;        // wave-uniform LDS bases (bytes: (2w+j)*1024)
  u16* ldsA1 = As + wave * 1024 + 512;
  u16* ldsB0 = Bs + wave * 1024;
  u16* ldsB1 = Bs + wave * 1024 + 512;
  // fragment read addresses: lane holds row (lane&15), k-base (lane>>4)*8
  const int lrow = lane & 15;
  const u16* fA = As + (wm * 64 + lrow) * 32 + (lane >> 4) * 8;
  const u16* fB = Bs + (wn * 64 + lrow) * 32 + (lane >> 4) * 8;

  const u16* PA[3] = {Ah, Ah, Al};
  const u16* PB[3] = {Bh, Bl, Bh};

  for (int ph = 0; ph < 3; ph++) {
    const u16* pa = PA[ph];
    const u16* pb = PB[ph];
    for (int kc = 0; kc < H_DIM; kc += 32) {
      __syncthreads();
      __builtin_amdgcn_global_load_lds((glb_u32*)(pa + (size_t)(m0 + rA0) * H_DIM + kc + ko0),
                                       (lds_u32*)ldsA0, 16, 0, 0);
      __builtin_amdgcn_global_load_lds((glb_u32*)(pa + (size_t)(m0 + rA1) * H_DIM + kc + ko1),
                                       (lds_u32*)ldsA1, 16, 0, 0);
      __builtin_amdgcn_global_load_lds((glb_u32*)(pb + (size_t)(n0 + rA0) * H_DIM + kc + ko0),
                                       (lds_u32*)ldsB0, 16, 0, 0);
      __builtin_amdgcn_global_load_lds((glb_u32*)(pb + (size_t)(n0 + rA1) * H_DIM + kc + ko1),
                                       (lds_u32*)ldsB1, 16, 0, 0);
      __syncthreads();  // compiler drains vmcnt before barrier
      bf16x8 a[4], b[4];
#pragma unroll
      for (int i = 0; i < 4; i++) a[i] = *(const bf16x8*)(fA + i * 512);
#pragma unroll
      for (int j = 0; j < 4; j++) b[j] = *(const bf16x8*)(fB + j * 512);
#pragma unroll
      for (int i = 0; i < 4; i++)
#pragma unroll
        for (int j = 0; j < 4; j++)
          acc[i][j] = __builtin_amdgcn_mfma_f32_16x16x32_bf16(a[i], b[j], acc[i][j], 0, 0, 0);
    }
  }

  // epilogue: C/D layout col=lane&15, row=(lane>>4)*4+reg  (m89-verified)
  const int rbase = m0 + wm * 64 + (lane >> 4) * 4;
  const int cbase = n0 + wn * 64 + lrow;
#pragma unroll
  for (int i = 0; i < 4; i++) {
#pragma unroll
    for (int j = 0; j < 4; j++) {
#pragma unroll
      for (int q = 0; q < 4; q++) {
        float v = acc[i][j][q];
        C[(size_t)(rbase + i * 16 + q) * NCOL + (cbase + j * 16)] = v;
        atomicAdd(&hist[fkey(v) >> 20], 1u);
      }
    }
  }
  __syncthreads();
  for (int bq = t; bq < 4096; bq += 256) {
    unsigned cc = hist[bq];
    if (cc) atomicAdd(&ghist[bq], cc);
  }
}

// ---------------- threshold: smallest bin b* s.t. count(key >= b*<<20) >= TOPK ----------------
__global__ __launch_bounds__(256) void find_thresh(const unsigned* __restrict__ ghist,
                                                   unsigned* __restrict__ thresh) {
  __shared__ unsigned part[256];
  const int t = threadIdx.x;
  unsigned s = 0;
#pragma unroll
  for (int b = 0; b < 16; b++) s += ghist[t * 16 + b];
  part[t] = s;
  __syncthreads();
  if (t == 0) {
    unsigned cum = 0;
    int g = 255;
    for (; g > 0; g--) {
      if (cum + part[g] >= TOPK) break;
      cum += part[g];
    }
    int bsel = g * 16;
    for (int b = g * 16 + 15; b >= g * 16; b--) {
      cum += ghist[b];
      if (cum >= TOPK) { bsel = b; break; }
    }
    *thresh = (unsigned)bsel << 20;
  }
}

// ---------------- collect candidates >= threshold (with margin), recompute EXACT fp32 value ----
// Exact recompute = sequential fmaf over k=0..255, identical order to the fp32 GEMM that
// matched the reference bitwise (absmax 0.0) -> topk ordering is exact.
__device__ __forceinline__ void cand_push(unsigned kapprox, unsigned thr_m, unsigned idx,
                                          const float* __restrict__ m0f,
                                          const float* __restrict__ m1f,
                                          unsigned long long* __restrict__ cand,
                                          unsigned* __restrict__ counter) {
  if (kapprox >= thr_m) {
    const unsigned row = idx >> 13;   // /8192
    const unsigned col = idx & 8191u; // %8192
    const float4* a4 = (const float4*)(m0f + (size_t)row * H_DIM);
    const float4* b4 = (const float4*)(m1f + (size_t)col * H_DIM);
    float v = 0.f;
#pragma unroll 8
    for (int k = 0; k < H_DIM / 4; k++) {
      float4 a = a4[k], b = b4[k];
      v = fmaf(a.x, b.x, v);
      v = fmaf(a.y, b.y, v);
      v = fmaf(a.z, b.z, v);
      v = fmaf(a.w, b.w, v);
    }
    unsigned p = atomicAdd(counter, 1u);
    if (p < CAND_CAP)
      cand[p] = ((unsigned long long)fkey(v) << 32) |
                (unsigned long long)(0xFFFFFFFFu - idx);
  }
}

__global__ __launch_bounds__(256) void collect(const float* __restrict__ sim,
                                               const unsigned* __restrict__ thresh,
                                               const float* __restrict__ m0f,
                                               const float* __restrict__ m1f,
                                               unsigned long long* __restrict__ cand,
                                               unsigned* __restrict__ counter) {
  const unsigned thr = *thresh;
  const unsigned thr_m = thr > 256u ? thr - 256u : 0u;  // 256-ulp margin covers bf16x3 error
  const int stride = gridDim.x * blockDim.x;
  const int total4 = (NCOL * NCOL) / 4;  // 16,777,216
  const float4* s4 = (const float4*)sim;
  for (int i = blockIdx.x * blockDim.x + threadIdx.x; i < total4; i += stride) {
    float4 v = s4[i];
    unsigned base = (unsigned)i * 4u;
    cand_push(fkey(v.x), thr_m, base + 0u, m0f, m1f, cand, counter);
    cand_push(fkey(v.y), thr_m, base + 1u, m0f, m1f, cand, counter);
    cand_push(fkey(v.z), thr_m, base + 2u, m0f, m1f, cand, counter);
    cand_push(fkey(v.w), thr_m, base + 3u, m0f, m1f, cand, counter);
  }
}

// ---------------- single-block bitonic sort of candidates, write top-512 (row,col) as floats ----
__global__ __launch_bounds__(1024) void sort_topk(const unsigned long long* __restrict__ cand,
                                                  const unsigned* __restrict__ counter,
                                                  float* __restrict__ out) {
  __shared__ unsigned long long s[CAND_CAP];  // 64KB
  const int t = threadIdx.x;
  int n = (int)min(*counter, (unsigned)CAND_CAP);
  int P = 512;
  while (P < n) P <<= 1;  // <= CAND_CAP
  for (int i = t; i < P; i += 1024) s[i] = (i < n) ? cand[i] : 0ULL;
  __syncthreads();
  for (int k = 2; k <= P; k <<= 1) {
    for (int j = k >> 1; j > 0; j >>= 1) {
      for (int i = t; i < P; i += 1024) {
        int l = i ^ j;
        if (l > i) {
          bool desc = ((i & k) == 0);
          unsigned long long a = s[i], b = s[l];
          bool sw = desc ? (a < b) : (a > b);
          if (sw) { s[i] = b; s[l] = a; }
        }
      }
      __syncthreads();
    }
  }
  if (t < TOPK) {
    unsigned long long c = s[t];
    unsigned idx = 0xFFFFFFFFu - (unsigned)(c & 0xFFFFFFFFull);
    unsigned row = idx >> 13;        // /8192
    unsigned col = idx & 8191u;      // %8192
    out[t * 2 + 0] = (float)row;
    out[t * 2 + 1] = (float)col;
  }
}

extern "C" void kernel_launch(void* const* d_in, const int* in_sizes, int n_in,
                              void* d_out, int out_size, void* d_ws, size_t ws_size,
                              hipStream_t stream) {
  const float* desc0 = (const float*)d_in[0];
  const float* desc1 = (const float*)d_in[1];
  const float* W0a = (const float*)d_in[2];
  const float* b0a = (const float*)d_in[3];
  const float* W0b = (const float*)d_in[4];
  const float* b0b = (const float*)d_in[5];
  const float* W1a = (const float*)d_in[6];
  const float* b1a = (const float*)d_in[7];
  const float* W1b = (const float*)d_in[8];
  const float* b1b = (const float*)d_in[9];

  char* ws = (char*)d_ws;
  unsigned* ghist = (unsigned*)ws;                                  // 16KB
  unsigned* counter = (unsigned*)(ws + 16384);                     // 4B
  unsigned* thresh = (unsigned*)(ws + 16388);                      // 4B
  unsigned long long* cand = (unsigned long long*)(ws + 16448);    // 64KB
  float* mdesc0f = (float*)(ws + 131072);                          // 8MB fp32 (exact recompute)
  float* mdesc1f = mdesc0f + 8192 * 256;                           // 8MB
  float* hbuf = mdesc1f + 8192 * 256;                              // 8MB
  u16* Ahh = (u16*)(hbuf + 8192 * 256);                            // 4MB bf16 hi
  u16* All = Ahh + 8192 * 256;                                     // 4MB bf16 lo
  u16* Bhh = All + 8192 * 256;                                     // 4MB
  u16* Bll = Bhh + 8192 * 256;                                     // 4MB  (total ~40MB)

  float* outf = (float*)d_out;
  float* sim = outf + TOPK * 2;  // sim at float offset 1024 (16B aligned)

  zero_ws<<<16, 256, 0, stream>>>(ghist, counter);

  mlp_layer<128, true, false><<<512, 256, 0, stream>>>(desc0, W0a, b0a, hbuf, nullptr, nullptr);
  mlp_layer<256, false, true><<<512, 256, 0, stream>>>(hbuf, W0b, b0b, mdesc0f, Ahh, All);
  mlp_layer<128, true, false><<<512, 256, 0, stream>>>(desc1, W1a, b1a, hbuf, nullptr, nullptr);
  mlp_layer<256, false, true><<<512, 256, 0, stream>>>(hbuf, W1b, b1b, mdesc1f, Bhh, Bll);

  gemm_sim_mfma<<<4096, 256, 0, stream>>>(Ahh, All, Bhh, Bll, sim, ghist);
  find_thresh<<<1, 256, 0, stream>>>(ghist, thresh);
  collect<<<4096, 256, 0, stream>>>(sim, thresh, mdesc0f, mdesc1f, cand, counter);
  sort_topk<<<1, 1024, 0, stream>>>(cand, counter, outf);
}